// Round 9
// baseline (320.816 us; speedup 1.0000x reference)
//
#include <hip/hip_runtime.h>
#include <hip/hip_bf16.h>

// ---------------------------------------------------------------------------
// attn_4329327035017: x[4,2048,1024] fp32 -> qkv GEMM -> causal MHA (16 heads,
// D=64) -> proj GEMM -> out fp32.
// R9: register-resident P. Swapped-QK^T C/D layout (lane holds P[q=l15]
// [k=lhi*4+j]) IS the A-operand layout of mfma_f32_16x16x16_bf16, so the
// cvt_pk dwords feed PV directly: no P LDS round-trip (was 8 ds_write + 4
// ds_read + lgkm serialization per tile). PV = 32x 16x16x16 MFMA, V B-frags
// via ds_read_b64 (2-way bank alias only). Psm dropped: LDS 49.7->33.3 KB ->
// 4 blocks/CU, grid 768->1024. Queue + longest-first kept from R8.
// ---------------------------------------------------------------------------

typedef __attribute__((ext_vector_type(8))) short bf16x8;
typedef __attribute__((ext_vector_type(4))) short bf16x4;
typedef __attribute__((ext_vector_type(4))) float f32x4;

#define NEGF -1e30f

__device__ __forceinline__ unsigned short f2bf(float f) {
    __hip_bfloat16 h = __float2bfloat16(f);
    unsigned short u;
    __builtin_memcpy(&u, &h, 2);
    return u;
}
// pack (a,b) -> one dword: a in low 16, b in high 16 (v_cvt_pk_bf16_f32)
__device__ __forceinline__ unsigned int f2bf2(float a, float b) {
    float2 t; t.x = a; t.y = b;
    __hip_bfloat162 r = __float22bfloat162_rn(t);
    unsigned int u;
    __builtin_memcpy(&u, &r, 4);
    return u;
}

__device__ __forceinline__ void async_copy16(const void* gsrc, void* ldsdst) {
    __builtin_amdgcn_global_load_lds(
        (const __attribute__((address_space(1))) unsigned int*)gsrc,
        (__attribute__((address_space(3))) unsigned int*)ldsdst,
        16, 0, 0);
}

// ---------------------------------------------------------------------------
// Conversions
// ---------------------------------------------------------------------------
__global__ void cvt_f32_bf16(const float* __restrict__ in,
                             unsigned short* __restrict__ out, int n) {
    int i = (blockIdx.x * 256 + threadIdx.x) * 4;
    if (i < n) {
        float4 v = *(const float4*)&in[i];
        uint2 o;
        o.x = f2bf2(v.x, v.y);
        o.y = f2bf2(v.z, v.w);
        *(uint2*)&out[i] = o;
    }
}

// in: [1024][N] fp32, out: [N][1024] bf16 (B^T layout). LDS-tiled transpose.
__global__ __launch_bounds__(256) void transpose_to_bf16(
    const float* __restrict__ in, unsigned short* __restrict__ out, int N) {
    __shared__ float tile[32][33];
    int ntiles_n = N >> 5;
    int tn = blockIdx.x % ntiles_n;
    int tk = blockIdx.x / ntiles_n;
    int r = threadIdx.x >> 5, c = threadIdx.x & 31;
#pragma unroll
    for (int rr = 0; rr < 32; rr += 8)
        tile[r + rr][c] = in[(size_t)(tk * 32 + r + rr) * N + tn * 32 + c];
    __syncthreads();
#pragma unroll
    for (int rr = 0; rr < 32; rr += 8)
        out[(size_t)(tn * 32 + r + rr) * 1024 + tk * 32 + c] =
            f2bf(tile[c][r + rr]);
}

// V [bh][2048][64] bf16 -> VT [bh][64][2048] bf16. LDS-tiled (64x64 tiles).
__global__ __launch_bounds__(256) void vtrans(
    const unsigned short* __restrict__ in, unsigned short* __restrict__ out) {
    __shared__ unsigned short t[64][65];
    int bh = blockIdx.x >> 5;
    int t0 = (blockIdx.x & 31) * 64;
    const unsigned short* ip = in + ((size_t)bh * 2048 + t0) * 64;
    unsigned short* op = out + (size_t)bh * 64 * 2048 + t0;
    int tid = threadIdx.x;
#pragma unroll
    for (int i = 0; i < 2; i++) {
        int chunk = i * 256 + tid;
        int row = chunk >> 3, c8 = (chunk & 7) * 8;
        bf16x8 v = *(const bf16x8*)&ip[row * 64 + c8];
#pragma unroll
        for (int jj = 0; jj < 8; jj++) t[row][c8 + jj] = (unsigned short)v[jj];
    }
    __syncthreads();
    int g = tid >> 6, lr = (tid & 63) >> 3, c8 = (tid & 7) * 8;
#pragma unroll
    for (int i = 0; i < 2; i++) {
        int d = i * 32 + g * 8 + lr;
        bf16x8 v;
#pragma unroll
        for (int jj = 0; jj < 8; jj++) v[jj] = (short)t[c8 + jj][d];
        *(bf16x8*)&op[(size_t)d * 2048 + c8] = v;
    }
}

// ---------------------------------------------------------------------------
// GEMM: C[M][N] = A[M][K] * BT[N][K]^T + bias
// MODE 0: scatter to Q/K/V bf16 [bh][T][D] (all row-major)
// MODE 1: fp32 out [M][N]
// ---------------------------------------------------------------------------
template <int MODE>
__global__ __launch_bounds__(256) void gemm_bf16(
    const unsigned short* __restrict__ A,
    const unsigned short* __restrict__ BT,
    const float* __restrict__ bias,
    float* __restrict__ Cout,
    unsigned short* __restrict__ Qb,
    unsigned short* __restrict__ Kb,
    unsigned short* __restrict__ Vb,
    int M, int N, int K, int tilesM) {
    __shared__ __align__(16) unsigned short As[128 * 64];
    __shared__ __align__(16) unsigned short Bs[128 * 64];

    int bid = blockIdx.x;
    int tm = bid % tilesM, tn = bid / tilesM;
    int m0 = tm * 128, n0 = tn * 128;
    int tid = threadIdx.x;
    int lane = tid & 63, wid = tid >> 6;
    int wr = wid >> 1, wc = wid & 1;
    int l15 = lane & 15, lhi = lane >> 4;

    f32x4 acc[4][4] = {};

    for (int k0 = 0; k0 < K; k0 += 64) {
#pragma unroll
        for (int r = 0; r < 4; r++) {
            int chunk = r * 256 + tid;
            int row = chunk >> 3, cc = chunk & 7;
            async_copy16(&A[(size_t)(m0 + row) * K + k0 + cc * 8],
                         (char*)As + chunk * 16);
        }
#pragma unroll
        for (int r = 0; r < 4; r++) {
            int chunk = r * 256 + tid;
            int row = chunk >> 3, cc = chunk & 7;
            async_copy16(&BT[(size_t)(n0 + row) * K + k0 + cc * 8],
                         (char*)Bs + chunk * 16);
        }
        __syncthreads();
#pragma unroll
        for (int kk = 0; kk < 2; kk++) {
            bf16x8 af[4], bfr[4];
#pragma unroll
            for (int mi = 0; mi < 4; mi++)
                af[mi] = *(const bf16x8*)&As[(wr * 64 + mi * 16 + l15) * 64 +
                                            kk * 32 + lhi * 8];
#pragma unroll
            for (int ni = 0; ni < 4; ni++)
                bfr[ni] = *(const bf16x8*)&Bs[(wc * 64 + ni * 16 + l15) * 64 +
                                              kk * 32 + lhi * 8];
#pragma unroll
            for (int mi = 0; mi < 4; mi++)
#pragma unroll
                for (int ni = 0; ni < 4; ni++)
                    acc[mi][ni] = __builtin_amdgcn_mfma_f32_16x16x32_bf16(
                        af[mi], bfr[ni], acc[mi][ni], 0, 0, 0);
        }
        __syncthreads();
    }

#pragma unroll
    for (int mi = 0; mi < 4; mi++)
#pragma unroll
        for (int ni = 0; ni < 4; ni++)
#pragma unroll
            for (int j = 0; j < 4; j++) {
                int gm = m0 + wr * 64 + mi * 16 + lhi * 4 + j;
                int gn = n0 + wc * 64 + ni * 16 + l15;
                float v = acc[mi][ni][j] + bias[gn];
                if (MODE == 0) {
                    int b = gm >> 11, t = gm & 2047;
                    int sel = gn >> 10, c = gn & 1023;
                    int h = c >> 6, d = c & 63;
                    int bh = b * 16 + h;
                    size_t idx = ((size_t)bh * 2048 + t) * 64 + d;
                    unsigned short bv = f2bf(v);
                    if (sel == 0) Qb[idx] = bv;
                    else if (sel == 1) Kb[idx] = bv;
                    else Vb[idx] = bv;
                } else {
                    Cout[(size_t)gm * N + gn] = v;
                }
            }
}

// ---------------------------------------------------------------------------
// Flash attention, causal, persistent. 1024 blocks x 4 waves pull (bh,qb)
// units from a global counter, longest-first. Per unit: QBLK=128, KVBLK=64;
// swapped QK^T (S^T via mfma(K,Q)) -> lane-resident softmax rows; defer-max;
// per-lane partial l; P stays in REGISTERS (cvt_pk dwords = 16x16x16 A-frag);
// PV = 32x mfma_f32_16x16x16_bf16 with V B-frags via ds_read_b64.
// LDS = 2x dbuf (K,V) = 32 KB -> 4 blocks/CU.
// ---------------------------------------------------------------------------
__global__ __launch_bounds__(256) void attn_kernel(
    const unsigned short* __restrict__ Qb,
    const unsigned short* __restrict__ Kb,
    const unsigned short* __restrict__ VTb,
    unsigned short* __restrict__ Aout,
    unsigned int* __restrict__ ctr) {
    __shared__ __align__(16) unsigned short Ksm[2][64 * 64];
    __shared__ __align__(16) unsigned short Vsm[2][64 * 64];
    __shared__ unsigned int s_unit;

    const float CSC = 0.18033688f;  // 0.125 * log2(e)

    int tid = threadIdx.x, lane = tid & 63, wid = tid >> 6;
    int l15 = lane & 15, lhi = lane >> 4;

    for (;;) {
        __syncthreads();                   // all threads done with prev unit
        if (tid == 0) s_unit = atomicAdd(ctr, 1u);
        __syncthreads();
        unsigned int u = s_unit;
        if (u >= 1024u) break;             // uniform exit

        int qb = 15 - (int)(u >> 6);       // longest work first
        int bh = (int)(u & 63u);
        int b = bh >> 4, h = bh & 15;

        const unsigned short* Qp = Qb + (size_t)bh * 2048 * 64;
        const unsigned short* Kp = Kb + (size_t)bh * 2048 * 64;
        const unsigned short* Vp = VTb + (size_t)bh * 64 * 2048;

        int qbase = qb * 128 + wid * 32;
        int qrow[2] = {qbase + l15, qbase + 16 + l15};

        bf16x8 aq[2][2];
#pragma unroll
        for (int mi = 0; mi < 2; mi++)
#pragma unroll
            for (int kk = 0; kk < 2; kk++)
                aq[mi][kk] = *(const bf16x8*)&Qp[(size_t)(qbase + mi * 16 + l15) *
                                                    64 + kk * 32 + lhi * 8];

        float m_s[2] = {NEGF, NEGF};     // running max, log2-scaled domain
        float2 l_p2[2];
        l_p2[0].x = 0.f; l_p2[0].y = 0.f; l_p2[1].x = 0.f; l_p2[1].y = 0.f;
        f32x4 o_acc[2][4] = {};

        int nkt = 2 * qb + 2;

        // prologue: stage tile 0 into buffer 0
#pragma unroll
        for (int r = 0; r < 2; r++) {
            int chunk = r * 256 + tid;
            int row = chunk >> 3;
            int el = (((chunk * 16) ^ ((row & 7) << 4)) & 127) >> 1;
            async_copy16(&Kp[(size_t)row * 64 + el], (char*)Ksm[0] + chunk * 16);
            async_copy16(&Vp[(size_t)row * 2048 + el], (char*)Vsm[0] + chunk * 16);
        }
        __syncthreads();

        for (int kt = 0; kt < nkt; kt++) {
            int cur = kt & 1;
            // ---- stage next tile into the other buffer
            if (kt + 1 < nkt) {
#pragma unroll
                for (int r = 0; r < 2; r++) {
                    int chunk = r * 256 + tid;
                    int row = chunk >> 3;
                    int el = (((chunk * 16) ^ ((row & 7) << 4)) & 127) >> 1;
                    async_copy16(&Kp[(size_t)((kt + 1) * 64 + row) * 64 + el],
                                 (char*)Ksm[cur ^ 1] + chunk * 16);
                    async_copy16(&Vp[(size_t)row * 2048 + (kt + 1) * 64 + el],
                                 (char*)Vsm[cur ^ 1] + chunk * 16);
                }
            }

            // ---- QK^T, swapped: s[mi][nt] = S^T block (rows=k, cols=q)
            f32x4 s[2][4] = {};
            __builtin_amdgcn_s_setprio(1);
#pragma unroll
            for (int kk = 0; kk < 2; kk++)
#pragma unroll
                for (int nt = 0; nt < 4; nt++) {
                    int row = nt * 16 + l15;
                    bf16x8 bk = *(const bf16x8*)((const char*)Ksm[cur] +
                        ((row * 128 + kk * 64 + lhi * 16) ^ ((row & 7) << 4)));
#pragma unroll
                    for (int mi = 0; mi < 2; mi++)
                        s[mi][nt] = __builtin_amdgcn_mfma_f32_16x16x32_bf16(
                            bk, aq[mi][kk], s[mi][nt], 0, 0, 0);
                }
            __builtin_amdgcn_s_setprio(0);

            // ---- causal mask (only last two tiles hit the diagonal)
            if (kt >= 2 * qb) {
#pragma unroll
                for (int mi = 0; mi < 2; mi++)
#pragma unroll
                    for (int nt = 0; nt < 4; nt++)
#pragma unroll
                        for (int j = 0; j < 4; j++) {
                            int kcol = kt * 64 + nt * 16 + lhi * 4 + j;
                            if (kcol > qrow[mi]) s[mi][nt][j] = NEGF;
                        }
            }

            // ---- row max: in-lane 16 values + 2 shfls
            float rmax_s[2];
#pragma unroll
            for (int mi = 0; mi < 2; mi++) {
                float r0 = fmaxf(fmaxf(s[mi][0][0], s[mi][0][1]),
                                 fmaxf(s[mi][0][2], s[mi][0][3]));
                float r1 = fmaxf(fmaxf(s[mi][1][0], s[mi][1][1]),
                                 fmaxf(s[mi][1][2], s[mi][1][3]));
                float r2 = fmaxf(fmaxf(s[mi][2][0], s[mi][2][1]),
                                 fmaxf(s[mi][2][2], s[mi][2][3]));
                float r3 = fmaxf(fmaxf(s[mi][3][0], s[mi][3][1]),
                                 fmaxf(s[mi][3][2], s[mi][3][3]));
                float rm = fmaxf(fmaxf(r0, r1), fmaxf(r2, r3));
                rm = fmaxf(rm, __shfl_xor(rm, 16, 64));
                rm = fmaxf(rm, __shfl_xor(rm, 32, 64));
                rmax_s[mi] = rm * CSC;
            }

            // ---- defer-max (T13)
            bool ok = (rmax_s[0] <= m_s[0] + 8.f) && (rmax_s[1] <= m_s[1] + 8.f);
            if (!__all(ok)) {
#pragma unroll
                for (int mi = 0; mi < 2; mi++) {
                    float mn = fmaxf(m_s[mi], rmax_s[mi]);
                    float sc = exp2f(m_s[mi] - mn);
                    m_s[mi] = mn;
                    l_p2[mi].x *= sc;
                    l_p2[mi].y *= sc;
#pragma unroll
                    for (int dt = 0; dt < 4; dt++)
#pragma unroll
                        for (int j = 0; j < 4; j++) o_acc[mi][dt][j] *= sc;
                }
            }

            // ---- P = exp2(s*CSC - m): cvt_pk dwords ARE the 16x16x16 A-frag
            bf16x4 pa[2][4];
#pragma unroll
            for (int mi = 0; mi < 2; mi++) {
                float msc = m_s[mi];
#pragma unroll
                for (int nt = 0; nt < 4; nt++) {
                    float p0 = exp2f(fmaf(s[mi][nt][0], CSC, -msc));
                    float p1 = exp2f(fmaf(s[mi][nt][1], CSC, -msc));
                    float p2 = exp2f(fmaf(s[mi][nt][2], CSC, -msc));
                    float p3 = exp2f(fmaf(s[mi][nt][3], CSC, -msc));
                    l_p2[mi].x += p0 + p2;
                    l_p2[mi].y += p1 + p3;
                    uint2 pk;
                    pk.x = f2bf2(p0, p1);
                    pk.y = f2bf2(p2, p3);
                    bf16x4 frag;
                    __builtin_memcpy(&frag, &pk, 8);
                    pa[mi][nt] = frag;
                }
            }

            // ---- PV: O[q][d] += P[q][k16] V[k16][d] per nt (K=16 MFMA)
            __builtin_amdgcn_s_setprio(1);
#pragma unroll
            for (int nt = 0; nt < 4; nt++) {
#pragma unroll
                for (int dt = 0; dt < 4; dt++) {
                    int vrow = dt * 16 + l15;
                    bf16x4 bv = *(const bf16x4*)((const char*)Vsm[cur] +
                        ((vrow * 128 + nt * 32 + lhi * 8) ^ ((vrow & 7) << 4)));
#pragma unroll
                    for (int mi = 0; mi < 2; mi++)
                        o_acc[mi][dt] = __builtin_amdgcn_mfma_f32_16x16x16bf16_1k(
                            pa[mi][nt], bv, o_acc[mi][dt], 0, 0, 0);
                }
            }
            __builtin_amdgcn_s_setprio(0);
            __syncthreads();   // implicit vmcnt(0): next tile's DMA has landed
        }

        // ---- epilogue
        float l_red[2];
#pragma unroll
        for (int mi = 0; mi < 2; mi++) {
            float l = l_p2[mi].x + l_p2[mi].y;
            l += __shfl_xor(l, 16, 64);
            l += __shfl_xor(l, 32, 64);
            l_red[mi] = l;
        }
#pragma unroll
        for (int mi = 0; mi < 2; mi++)
#pragma unroll
            for (int j = 0; j < 4; j++) {
                float l = __shfl(l_red[mi], lhi * 4 + j, 64);
                float rinv = 1.f / l;
                int t = qbase + mi * 16 + lhi * 4 + j;
#pragma unroll
                for (int dt = 0; dt < 4; dt++) {
                    int cc = h * 64 + dt * 16 + l15;
                    Aout[((size_t)b * 2048 + t) * 1024 + cc] =
                        f2bf(o_acc[mi][dt][j] * rinv);
                }
            }
    }
}

// ---------------------------------------------------------------------------
extern "C" void kernel_launch(void* const* d_in, const int* in_sizes, int n_in,
                              void* d_out, int out_size, void* d_ws,
                              size_t ws_size, hipStream_t stream) {
    const float* x = (const float*)d_in[0];       // [4,2048,1024]
    const float* W_attn = (const float*)d_in[1];  // [1024,3072]
    const float* b_attn = (const float*)d_in[2];  // [3072]
    const float* W_proj = (const float*)d_in[3];  // [1024,1024]
    const float* b_proj = (const float*)d_in[4];  // [1024]
    float* out = (float*)d_out;                   // [4,2048,1024]

    char* ws = (char*)d_ws;
    const size_t MB = 1 << 20;
    unsigned short* xb  = (unsigned short*)(ws + 0);        // 16MB [8192][1024]
    unsigned short* VTb = (unsigned short*)(ws + 0);        // reuse post-GEMM1
    unsigned short* WaT = (unsigned short*)(ws + 16 * MB);  // 6MB
    unsigned short* WpT = (unsigned short*)(ws + 22 * MB);  // 2MB
    unsigned short* Qb  = (unsigned short*)(ws + 24 * MB);  // 16MB [64][2048][64]
    unsigned short* Kb  = (unsigned short*)(ws + 40 * MB);  // 16MB [64][2048][64]
    unsigned short* Vb  = (unsigned short*)(ws + 56 * MB);  // 16MB [64][2048][64]
    unsigned short* Att = (unsigned short*)(ws + 72 * MB);  // 16MB [8192][1024]
    unsigned int*   ctr = (unsigned int*)(ws + 56 * MB);    // Vb dead post-vtrans

    const int Mtok = 8192;

    cvt_f32_bf16<<<8192, 256, 0, stream>>>(x, xb, Mtok * 1024);
    transpose_to_bf16<<<96 * 32, 256, 0, stream>>>(W_attn, WaT, 3072);
    transpose_to_bf16<<<32 * 32, 256, 0, stream>>>(W_proj, WpT, 1024);

    // qkv GEMM: M=8192, N=3072, K=1024 -> Q/K/V (all row-major)
    gemm_bf16<0><<<64 * 24, 256, 0, stream>>>(xb, WaT, b_attn, nullptr, Qb, Kb,
                                              Vb, Mtok, 3072, 1024, 64);

    // V [bh][t][d] -> VT [bh][d][t]  (xb region is free now)
    vtrans<<<64 * 32, 256, 0, stream>>>(Vb, VTb);

    // work-queue counter := 0 (Vb region is dead after vtrans; stream-ordered)
    hipMemsetAsync(ctr, 0, sizeof(unsigned int), stream);

    // causal attention: persistent, 4 blocks/CU (32 KB LDS)
    attn_kernel<<<1024, 256, 0, stream>>>(Qb, Kb, VTb, Att, ctr);

    // proj GEMM: M=8192, N=1024, K=1024 -> fp32 out
    gemm_bf16<1><<<64 * 8, 256, 0, stream>>>(Att, WpT, b_proj, out, nullptr,
                                             nullptr, nullptr, Mtok, 1024, 1024,
                                             64);
}